// Round 3
// baseline (262.365 us; speedup 1.0000x reference)
//
#include <hip/hip_runtime.h>

#define TREES 64
#define NN 63        // internal nodes per tree
#define LL 64        // leaves per tree
#define CC 100       // classes
#define CPAD 112     // classes padded to 7*16
#define DD 512       // feature dim
#define BB 8192      // batch

typedef __attribute__((ext_vector_type(8))) _Float16 f16x8;
typedef __attribute__((ext_vector_type(4))) _Float16 f16x4;
typedef __attribute__((ext_vector_type(4))) float floatx4;

// ---- workspace layout (bytes) ----
#define XH_WS   0            // x  tiled: [64 rb][8 kt][128 row][8 c][8] f16 = 8 MB
#define SWH_WS  8388608      // sw tiled: [32 cb][8 kt][128 col][8 c][8] f16 = 4 MB
#define W2T_WS  12582912     // [64 t][112 c][64 l] f16 (chunk-swizzled) = 0.92 MB

__device__ __forceinline__ void gl_lds16(const _Float16* g, char* lds) {
    __builtin_amdgcn_global_load_lds(
        (const __attribute__((address_space(1))) unsigned int*)g,
        (__attribute__((address_space(3))) unsigned int*)lds, 16, 0, 0);
}

__device__ __forceinline__ f16x8 cvt8(const float* s) {
    float4 a = *(const float4*)s, b = *(const float4*)(s + 4);
    f16x8 h;
    h[0]=(_Float16)a.x; h[1]=(_Float16)a.y; h[2]=(_Float16)a.z; h[3]=(_Float16)a.w;
    h[4]=(_Float16)b.x; h[5]=(_Float16)b.y; h[6]=(_Float16)b.z; h[7]=(_Float16)b.w;
    return h;
}

// fast sigmoid: rcp is 1-ulp accurate; result rounds to f16 anyway
__device__ __forceinline__ float fsig(float x) {
    return __builtin_amdgcn_rcpf(1.f + __expf(-x));
}

// ---------------------------------------------------------------------------
// Prep (merged): blocks 0..3071 tile+convert x/sw; blocks 3072..4095 build
// w2T[t][c][l'] with leaf chunk pre-swizzled; blocks 4096..4895 zero `out`
// (REQUIRED: fused kernel accumulates into out with atomics).
// ---------------------------------------------------------------------------
__global__ __launch_bounds__(256) void prep_kernel(
    const float* __restrict__ x, const float* __restrict__ sw,
    const float* __restrict__ leaf_logits, const float* __restrict__ tree_w,
    _Float16* __restrict__ xh, _Float16* __restrict__ swh,
    _Float16* __restrict__ w2T, float* __restrict__ out)
{
    if (blockIdx.x < 3072) {
        int i = blockIdx.x * 256 + threadIdx.x;
        if (i < 524288) {                        // x: 64rb*8kt*1024 chunks
            int tile = i >> 10, cidx = i & 1023;
            int row = cidx >> 3, c = cidx & 7;
            int rb = tile >> 3, kt = tile & 7;
            int gk = kt * 64 + ((c ^ (row & 7)) << 3);
            *(f16x8*)(xh + (size_t)i * 8) = cvt8(x + (size_t)(rb * 128 + row) * DD + gk);
        } else {
            int j = i - 524288;                  // sw: 32cb*8kt*1024 chunks
            if (j < 262144) {
                int tile = j >> 10, cidx = j & 1023;
                int col = cidx >> 3, c = cidx & 7;
                int cb = tile >> 3, kt = tile & 7;
                int tt = col >> 6, node = col & 63;
                f16x8 h = (f16x8)(_Float16)0.f;
                if (node < NN) {
                    int gk = kt * 64 + ((c ^ (col & 7)) << 3);
                    h = cvt8(sw + (size_t)((cb * 2 + tt) * NN + node) * DD + gk);
                }
                *(f16x8*)(swh + (size_t)j * 8) = h;
            }
        }
    } else if (blockIdx.x < 4096) {
        int row  = (blockIdx.x - 3072) * 4 + (threadIdx.x >> 6);  // t*64 + l
        int lane = threadIdx.x & 63;
        int t = row >> 6, l = row & 63;
        const float* src = leaf_logits + (size_t)row * CC;
        float v0 = (lane < CC)      ? src[lane]      : -1e30f;
        float v1 = (lane + 64 < CC) ? src[lane + 64] : -1e30f;
        float m = fmaxf(v0, v1);
#pragma unroll
        for (int off = 32; off > 0; off >>= 1)
            m = fmaxf(m, __shfl_down(m, off, 64));
        m = __shfl(m, 0, 64);
        float e0 = (lane < CC)      ? __expf(v0 - m) : 0.f;
        float e1 = (lane + 64 < CC) ? __expf(v1 - m) : 0.f;
        float s = e0 + e1;
#pragma unroll
        for (int off = 32; off > 0; off >>= 1)
            s += __shfl_down(s, off, 64);
        s = __shfl(s, 0, 64);
        float scale = tree_w[t] / s;
        _Float16* base = w2T + (size_t)t * CPAD * LL;
#define LSWZ(c) ((((l >> 3) ^ ((c) & 7)) << 3) | (l & 7))
        if (lane < CC)      base[(size_t)lane * LL + LSWZ(lane)]               = (_Float16)(e0 * scale);
        if (lane + 64 < CC) base[(size_t)(lane + 64) * LL + LSWZ(lane + 64)]   = (_Float16)(e1 * scale);
        if (lane < CPAD - CC) base[(size_t)(CC + lane) * LL + LSWZ(CC + lane)] = (_Float16)0.f;
#undef LSWZ
    } else {
        // zero out[8192][100]: 800 blocks * 256 thr * 4 floats = 819200
        int i = (blockIdx.x - 4096) * 1024 + threadIdx.x * 4;
        *(float4*)(out + i) = make_float4(0.f, 0.f, 0.f, 0.f);
    }
}

// ---------------------------------------------------------------------------
// Fused kernel = R0's proven gemm1 body (grid 64x32, 256 thr, 4 waves 2x2,
// 62us measured) with the lp HBM store replaced by a GEMM2 partial:
// A-frags from lpl in LDS (R1-proven swizzled read), B-frags from
// L2-resident w2T, then unsafeAtomicAdd of the 128x112 2-tree partial into
// out (32-way across tc; same-rb blocks land on the same XCD under the %8
// round-robin, and this atomic path passed in R1/R2).
// ---------------------------------------------------------------------------
#define A_SMEM 33280
__global__ __launch_bounds__(256, 4) void fused_kernel(
    const _Float16* __restrict__ xh,
    const _Float16* __restrict__ swh,
    const float* __restrict__ sb,
    const _Float16* __restrict__ w2T,
    float* __restrict__ out)
{
    __shared__ __align__(16) char smem[A_SMEM];
    _Float16* xs  = (_Float16*)smem;             // [128][64] staging
    _Float16* wl  = (_Float16*)(smem + 16384);   // [128][64] staging
    _Float16* dec = (_Float16*)smem;             // [128 col][130] logits (alias)
    _Float16* lpl = (_Float16*)smem;             // [2][128][8 slot][8] (alias)

    const int tid  = threadIdx.x;
    const int lane = tid & 63;
    const int wid  = tid >> 6;
    const int wy   = wid >> 1;
    const int wx   = wid & 1;
    const int quad = lane >> 4;
    const int l15  = lane & 15;
    const int rb   = blockIdx.x;
    const int cb   = blockIdx.y;

    float bias_v[4];
    {
        int mytree = cb * 2 + wx;
#pragma unroll
        for (int ni = 0; ni < 4; ++ni) {
            int nd = 16 * ni + l15;
            bias_v[ni] = (nd < NN) ? sb[mytree * NN + nd] : 0.f;
        }
    }

    floatx4 acc[4][4];
#pragma unroll
    for (int i = 0; i < 4; ++i)
#pragma unroll
        for (int j = 0; j < 4; ++j) acc[i][j] = (floatx4)0.f;

    const _Float16* xtile = xh + (size_t)rb * 8 * 8192;
    const _Float16* wtile = swh + (size_t)cb * 8 * 8192;

    for (int kt = 0; kt < 8; ++kt) {
        __syncthreads();   // previous tile's frag reads done
#pragma unroll
        for (int j = 0; j < 4; ++j) {   // fully coalesced 1KB per instr
            gl_lds16(xtile + kt * 8192 + j * 2048 + wid * 512 + lane * 8,
                     smem + j * 4096 + wid * 1024);
            gl_lds16(wtile + kt * 8192 + j * 2048 + wid * 512 + lane * 8,
                     smem + 16384 + j * 4096 + wid * 1024);
        }
        __syncthreads();   // vmcnt(0) drain: tile visible
#pragma unroll
        for (int ks = 0; ks < 2; ++ks) {
            f16x8 af[4], bf[4];
#pragma unroll
            for (int mi = 0; mi < 4; ++mi) {
                int r = 64 * wy + 16 * mi + l15;
                af[mi] = *(const f16x8*)&xs[r * 64 + ((((ks << 2) | quad) ^ (r & 7)) << 3)];
            }
#pragma unroll
            for (int ni = 0; ni < 4; ++ni) {
                int r = 64 * wx + 16 * ni + l15;
                bf[ni] = *(const f16x8*)&wl[r * 64 + ((((ks << 2) | quad) ^ (r & 7)) << 3)];
            }
#pragma unroll
            for (int mi = 0; mi < 4; ++mi)
#pragma unroll
                for (int ni = 0; ni < 4; ++ni)
                    acc[mi][ni] = __builtin_amdgcn_mfma_f32_16x16x32_f16(
                        af[mi], bf[ni], acc[mi][ni], 0, 0, 0);
        }
    }
    __syncthreads();   // staging dead -> dec aliases it

    // biased logits -> dec[col][row], f16x4 packed stores
#pragma unroll
    for (int mi = 0; mi < 4; ++mi) {
        int r0 = 64 * wy + 16 * mi + 4 * quad;
#pragma unroll
        for (int ni = 0; ni < 4; ++ni) {
            int col = 64 * wx + 16 * ni + l15;
            f16x4 v;
#pragma unroll
            for (int r = 0; r < 4; ++r)
                v[r] = (_Float16)(acc[mi][ni][r] + bias_v[ni]);
            *(f16x4*)&dec[col * 130 + r0] = v;
        }
    }
    __syncthreads();

    // leafprob: thread = (tree tt, row lrow); fast sigmoid inline
    const int tt   = tid >> 7;
    const int lrow = tid & 127;
    const int tb   = tt * 64;
    f16x8 lpreg[8];
    {
#define SIG(n) fsig((float)dec[(tb + (n)) * 130 + lrow])
        float d0 = SIG(0);
#pragma unroll
        for (int h = 0; h < 2; ++h) {
            float p1 = h ? d0 : 1.f - d0;
            float d1 = SIG(1 + h);
#pragma unroll
            for (int b8 = 0; b8 < 4; ++b8) {
                int i4 = b8 >> 1, i3 = b8 & 1;
                float p2 = p1 * (i4 ? d1 : 1.f - d1);
                float d2 = SIG(3 + 2 * h + i4);
                float p3 = p2 * (i3 ? d2 : 1.f - d2);
                float d3 = SIG(7 + 4 * h + b8);
                f16x8 blk;
#pragma unroll
                for (int i2 = 0; i2 < 2; ++i2) {
                    float p4 = p3 * (i2 ? d3 : 1.f - d3);
                    float d4 = SIG(15 + 8 * h + 2 * b8 + i2);
#pragma unroll
                    for (int i1 = 0; i1 < 2; ++i1) {
                        float p5 = p4 * (i1 ? d4 : 1.f - d4);
                        float d5 = SIG(31 + 16 * h + 4 * b8 + 2 * i2 + i1);
                        blk[i2 * 4 + i1 * 2 + 0] = (_Float16)(p5 * (1.f - d5));
                        blk[i2 * 4 + i1 * 2 + 1] = (_Float16)(p5 * d5);
                    }
                }
                lpreg[h * 4 + b8] = blk;
            }
        }
#undef SIG
    }
    __syncthreads();   // all dec reads done -> lpl aliases it

#pragma unroll
    for (int q = 0; q < 8; ++q)
        *(f16x8*)&lpl[tt * 8192 + lrow * 64 + ((q ^ (lrow & 7)) << 3)] = lpreg[q];
    __syncthreads();   // lpl visible

    // ---- GEMM2 partial: oacc2 += lpl[this wave's 32 rows] @ w2T[2 trees]
    // A-frag read = same swizzled-chunk pattern as xs/wl (conflict-free);
    // B direct from global w2T (L2-resident, 0.92 MB total).
    floatx4 oacc2[2][7];
#pragma unroll
    for (int mi = 0; mi < 2; ++mi)
#pragma unroll
        for (int ni = 0; ni < 7; ++ni) oacc2[mi][ni] = (floatx4)0.f;
    {
        const int tree0 = cb * 2;
        const int rbase = wid * 32;
#pragma unroll
        for (int t = 0; t < 2; ++t) {
            const _Float16* bp = w2T + (size_t)(tree0 + t) * (CPAD * LL) + (size_t)l15 * 64;
            const _Float16* lplt = lpl + t * 8192;
#pragma unroll
            for (int ks = 0; ks < 2; ++ks) {
                const int sw = (((ks << 2) | quad) ^ (l15 & 7)) << 3;
                f16x8 bbv[7], abv[2];
#pragma unroll
                for (int ni = 0; ni < 7; ++ni)       // global first (latency)
                    bbv[ni] = *(const f16x8*)(bp + ni * 16 * 64 + sw);
#pragma unroll
                for (int mi = 0; mi < 2; ++mi) {
                    int r = rbase + 16 * mi + l15;   // r&7 == l15&7
                    abv[mi] = *(const f16x8*)&lplt[r * 64 + sw];
                }
#pragma unroll
                for (int mi = 0; mi < 2; ++mi)
#pragma unroll
                    for (int ni = 0; ni < 7; ++ni)
                        oacc2[mi][ni] = __builtin_amdgcn_mfma_f32_16x16x32_f16(
                            abv[mi], bbv[ni], oacc2[mi][ni], 0, 0, 0);
            }
        }
    }

    // ---- epilogue: atomically accumulate this block's 128x112 2-tree
    // partial. C layout: row = 16*mi + 4*quad + r, col = 16*ni + l15.
    {
        const int rbase2 = rb * 128 + wid * 32 + 4 * quad;
#pragma unroll
        for (int mi = 0; mi < 2; ++mi)
#pragma unroll
            for (int ni = 0; ni < 7; ++ni) {
                int col = 16 * ni + l15;
                if (col < CC) {
#pragma unroll
                    for (int r = 0; r < 4; ++r)
                        unsafeAtomicAdd(&out[(size_t)(rbase2 + 16 * mi + r) * CC + col],
                                        oacc2[mi][ni][r]);
                }
            }
    }
}

// ---------------------------------------------------------------------------
extern "C" void kernel_launch(void* const* d_in, const int* in_sizes, int n_in,
                              void* d_out, int out_size, void* d_ws, size_t ws_size,
                              hipStream_t stream) {
    const float* x  = (const float*)d_in[0];   // [8192][512]
    const float* sw = (const float*)d_in[1];   // [64][63][512]
    const float* sb = (const float*)d_in[2];   // [64][63]
    const float* ll = (const float*)d_in[3];   // [64][64][100]
    const float* tw = (const float*)d_in[4];   // [64]
    float* out = (float*)d_out;                // [8192][100]
    _Float16* xh  = (_Float16*)((char*)d_ws + XH_WS);
    _Float16* swh = (_Float16*)((char*)d_ws + SWH_WS);
    _Float16* w2T = (_Float16*)((char*)d_ws + W2T_WS);

    prep_kernel<<<dim3(4896), 256, 0, stream>>>(x, sw, ll, tw, xh, swh, w2T, out);
    fused_kernel<<<dim3(64, 32), 256, 0, stream>>>(xh, swh, sb, w2T, out);
}

// Round 4
// 169.952 us; speedup vs baseline: 1.5438x; 1.5438x over previous
//
#include <hip/hip_runtime.h>

#define TREES 64
#define NN 63        // internal nodes per tree
#define LL 64        // leaves per tree
#define CC 100       // classes
#define CPAD 112     // classes padded to 7*16
#define DD 512       // feature dim
#define BB 8192      // batch

typedef __attribute__((ext_vector_type(8))) _Float16 f16x8;
typedef __attribute__((ext_vector_type(4))) _Float16 f16x4;
typedef __attribute__((ext_vector_type(4))) float floatx4;

// ---- workspace layout (bytes) ----
#define XH_WS   0            // x  tiled: [64 rb][8 kt][128 row][8 c][8] f16 = 8 MB
#define SWH_WS  8388608      // sw tiled: [32 cb][8 kt][128 col][8 c][8] f16 = 4 MB
#define W2T_WS  12582912     // [64 t][112 c][64 l] f16 (chunk-swizzled) = 0.92 MB

__device__ __forceinline__ void gl_lds16(const _Float16* g, char* lds) {
    __builtin_amdgcn_global_load_lds(
        (const __attribute__((address_space(1))) unsigned int*)g,
        (__attribute__((address_space(3))) unsigned int*)lds, 16, 0, 0);
}

__device__ __forceinline__ f16x8 cvt8(const float* s) {
    float4 a = *(const float4*)s, b = *(const float4*)(s + 4);
    f16x8 h;
    h[0]=(_Float16)a.x; h[1]=(_Float16)a.y; h[2]=(_Float16)a.z; h[3]=(_Float16)a.w;
    h[4]=(_Float16)b.x; h[5]=(_Float16)b.y; h[6]=(_Float16)b.z; h[7]=(_Float16)b.w;
    return h;
}

// fast sigmoid: rcp is 1-ulp accurate; result rounds to f16 anyway
__device__ __forceinline__ float fsig(float x) {
    return __builtin_amdgcn_rcpf(1.f + __expf(-x));
}

// ---------------------------------------------------------------------------
// Prep (merged): blocks 0..3071 tile+convert x/sw; blocks 3072..4095 build
// w2T[t][c][l'] with leaf chunk pre-swizzled; blocks 4096..4895 zero `out`
// (REQUIRED: fused kernel accumulates into out with atomics).
// ---------------------------------------------------------------------------
__global__ __launch_bounds__(256) void prep_kernel(
    const float* __restrict__ x, const float* __restrict__ sw,
    const float* __restrict__ leaf_logits, const float* __restrict__ tree_w,
    _Float16* __restrict__ xh, _Float16* __restrict__ swh,
    _Float16* __restrict__ w2T, float* __restrict__ out)
{
    if (blockIdx.x < 3072) {
        int i = blockIdx.x * 256 + threadIdx.x;
        if (i < 524288) {                        // x: 64rb*8kt*1024 chunks
            int tile = i >> 10, cidx = i & 1023;
            int row = cidx >> 3, c = cidx & 7;
            int rb = tile >> 3, kt = tile & 7;
            int gk = kt * 64 + ((c ^ (row & 7)) << 3);
            *(f16x8*)(xh + (size_t)i * 8) = cvt8(x + (size_t)(rb * 128 + row) * DD + gk);
        } else {
            int j = i - 524288;                  // sw: 32cb*8kt*1024 chunks
            if (j < 262144) {
                int tile = j >> 10, cidx = j & 1023;
                int col = cidx >> 3, c = cidx & 7;
                int cb = tile >> 3, kt = tile & 7;
                int tt = col >> 6, node = col & 63;
                f16x8 h = (f16x8)(_Float16)0.f;
                if (node < NN) {
                    int gk = kt * 64 + ((c ^ (col & 7)) << 3);
                    h = cvt8(sw + (size_t)((cb * 2 + tt) * NN + node) * DD + gk);
                }
                *(f16x8*)(swh + (size_t)j * 8) = h;
            }
        }
    } else if (blockIdx.x < 4096) {
        int row  = (blockIdx.x - 3072) * 4 + (threadIdx.x >> 6);  // t*64 + l
        int lane = threadIdx.x & 63;
        int t = row >> 6, l = row & 63;
        const float* src = leaf_logits + (size_t)row * CC;
        float v0 = (lane < CC)      ? src[lane]      : -1e30f;
        float v1 = (lane + 64 < CC) ? src[lane + 64] : -1e30f;
        float m = fmaxf(v0, v1);
#pragma unroll
        for (int off = 32; off > 0; off >>= 1)
            m = fmaxf(m, __shfl_down(m, off, 64));
        m = __shfl(m, 0, 64);
        float e0 = (lane < CC)      ? __expf(v0 - m) : 0.f;
        float e1 = (lane + 64 < CC) ? __expf(v1 - m) : 0.f;
        float s = e0 + e1;
#pragma unroll
        for (int off = 32; off > 0; off >>= 1)
            s += __shfl_down(s, off, 64);
        s = __shfl(s, 0, 64);
        float scale = tree_w[t] / s;
        _Float16* base = w2T + (size_t)t * CPAD * LL;
#define LSWZ(c) ((((l >> 3) ^ ((c) & 7)) << 3) | (l & 7))
        if (lane < CC)      base[(size_t)lane * LL + LSWZ(lane)]               = (_Float16)(e0 * scale);
        if (lane + 64 < CC) base[(size_t)(lane + 64) * LL + LSWZ(lane + 64)]   = (_Float16)(e1 * scale);
        if (lane < CPAD - CC) base[(size_t)(CC + lane) * LL + LSWZ(CC + lane)] = (_Float16)0.f;
#undef LSWZ
    } else {
        // zero out[8192][100]: 800 blocks * 256 thr * 4 floats = 819200
        int i = (blockIdx.x - 4096) * 1024 + threadIdx.x * 4;
        *(float4*)(out + i) = make_float4(0.f, 0.f, 0.f, 0.f);
    }
}

// ---------------------------------------------------------------------------
// Fused kernel R4: grid (128 rowblocks of 64 rows, 8 treechunks), 256 thr
// (4 waves). Block = 64 rows x 8 trees, tg-loop over 4 two-tree groups.
// GEMM1 tile 64x128 (wave = 64 rows x 32 cols, acc[4][2]); LDS 24KB ->
// 4 blocks/CU = 16 waves/CU (2x R1's occupancy, which was the R1 killer).
// Atomic budget = R1's proven-benign 7.3M adds (8 writers/element), NOT
// R3's 29M/32-writer disaster (WRITE 176MB).
// xh half-tiles: rb2 = rb>>1, half offset 4096 elems/kt; row&7 swizzle
// invariant under +64 so all chunk swizzles unchanged.
// ---------------------------------------------------------------------------
#define A_SMEM 24576
__global__ __launch_bounds__(256, 4) void fused_kernel(
    const _Float16* __restrict__ xh,
    const _Float16* __restrict__ swh,
    const float* __restrict__ sb,
    const _Float16* __restrict__ w2T,
    float* __restrict__ out)
{
    __shared__ __align__(16) char smem[A_SMEM];
    _Float16* xs  = (_Float16*)smem;             // [64][64] staging
    _Float16* wl  = (_Float16*)(smem + 8192);    // [128][64] staging
    _Float16* dec = (_Float16*)smem;             // [128 col][66] logits (alias)
    _Float16* lpl = (_Float16*)smem;             // [2][64][8 slot][8] (alias)

    const int tid  = threadIdx.x;
    const int lane = tid & 63;
    const int wid  = tid >> 6;            // 0..3 : 32-col slice of GEMM1
    const int quad = lane >> 4;
    const int l15  = lane & 15;
    const int rb   = blockIdx.x;          // 0..127 : 64-row block
    const int tc   = blockIdx.y;          // 0..7   : 8-tree chunk
    const int rb2  = rb >> 1;
    const int half = rb & 1;

    // GEMM2 accumulator: wave wid owns rows [wid*16, wid*16+16) x 112 cols
    floatx4 oacc2[7];
#pragma unroll
    for (int ni = 0; ni < 7; ++ni) oacc2[ni] = (floatx4)0.f;

    const _Float16* xtile = xh + (size_t)rb2 * 65536 + (size_t)half * 4096;

    for (int tg = 0; tg < 4; ++tg) {
        const int cb = tc * 4 + tg;              // 0..31, covers 2 trees
        const _Float16* wtile = swh + (size_t)cb * 65536;

        float bias_v[2];
        {
            int mytree = cb * 2 + (wid >> 1);
#pragma unroll
            for (int ni = 0; ni < 2; ++ni) {
                int nd = 32 * (wid & 1) + 16 * ni + l15;
                bias_v[ni] = (nd < NN) ? sb[mytree * NN + nd] : 0.f;
            }
        }

        floatx4 acc[4][2];
#pragma unroll
        for (int i = 0; i < 4; ++i)
#pragma unroll
            for (int j = 0; j < 2; ++j) acc[i][j] = (floatx4)0.f;

        for (int kt = 0; kt < 8; ++kt) {
            __syncthreads();   // prev frag/lpl reads done
#pragma unroll
            for (int j = 0; j < 2; ++j)     // x: 64 rows x 64 k = 8KB
                gl_lds16(xtile + kt * 8192 + j * 2048 + wid * 512 + lane * 8,
                         smem + j * 4096 + wid * 1024);
#pragma unroll
            for (int j = 0; j < 4; ++j)     // w: 128 cols x 64 k = 16KB
                gl_lds16(wtile + kt * 8192 + j * 2048 + wid * 512 + lane * 8,
                         smem + 8192 + j * 4096 + wid * 1024);
            __syncthreads();   // vmcnt(0) drain: tile visible
#pragma unroll
            for (int ks = 0; ks < 2; ++ks) {
                f16x8 af[4], bf[2];
#pragma unroll
                for (int mi = 0; mi < 4; ++mi) {
                    int r = 16 * mi + l15;
                    af[mi] = *(const f16x8*)&xs[r * 64 + ((((ks << 2) | quad) ^ (r & 7)) << 3)];
                }
#pragma unroll
                for (int ni = 0; ni < 2; ++ni) {
                    int r = 32 * wid + 16 * ni + l15;
                    bf[ni] = *(const f16x8*)&wl[r * 64 + ((((ks << 2) | quad) ^ (r & 7)) << 3)];
                }
#pragma unroll
                for (int mi = 0; mi < 4; ++mi)
#pragma unroll
                    for (int ni = 0; ni < 2; ++ni)
                        acc[mi][ni] = __builtin_amdgcn_mfma_f32_16x16x32_f16(
                            af[mi], bf[ni], acc[mi][ni], 0, 0, 0);
            }
        }
        __syncthreads();   // staging dead -> dec aliases it

        // biased logits -> dec[col][row], f16x4 packed stores (stride 66:
        // col-step = 132B = 33 banks -> 16 lanes hit distinct banks)
#pragma unroll
        for (int mi = 0; mi < 4; ++mi) {
            int r0 = 16 * mi + 4 * quad;
#pragma unroll
            for (int ni = 0; ni < 2; ++ni) {
                int col = 32 * wid + 16 * ni + l15;
                f16x4 v;
#pragma unroll
                for (int r = 0; r < 4; ++r)
                    v[r] = (_Float16)(acc[mi][ni][r] + bias_v[ni]);
                *(f16x4*)&dec[col * 66 + r0] = v;
            }
        }
        __syncthreads();

        // leafprob: thread = (half u, tree tt, row lrow); each thread does
        // one h-half of its tree (4 of the 8 leaf chunks). R2-proven split.
        const int u    = tid >> 7;            // 0..1 : which h-half
        const int tt   = (tid >> 6) & 1;
        const int lrow = tid & 63;
        const int tb   = tt * 64;
        f16x8 lpreg[4];
        {
#define SIG(n) fsig((float)dec[(tb + (n)) * 66 + lrow])
            float d0 = SIG(0);
            float p1 = u ? d0 : 1.f - d0;
            float d1 = SIG(1 + u);
#pragma unroll
            for (int b8 = 0; b8 < 4; ++b8) {
                int i4 = b8 >> 1, i3 = b8 & 1;
                float p2 = p1 * (i4 ? d1 : 1.f - d1);
                float d2 = SIG(3 + 2 * u + i4);
                float p3 = p2 * (i3 ? d2 : 1.f - d2);
                float d3 = SIG(7 + 4 * u + b8);
                f16x8 blk;
#pragma unroll
                for (int i2 = 0; i2 < 2; ++i2) {
                    float p4 = p3 * (i2 ? d3 : 1.f - d3);
                    float d4 = SIG(15 + 8 * u + 2 * b8 + i2);
#pragma unroll
                    for (int i1 = 0; i1 < 2; ++i1) {
                        float p5 = p4 * (i1 ? d4 : 1.f - d4);
                        float d5 = SIG(31 + 16 * u + 4 * b8 + 2 * i2 + i1);
                        blk[i2 * 4 + i1 * 2 + 0] = (_Float16)(p5 * (1.f - d5));
                        blk[i2 * 4 + i1 * 2 + 1] = (_Float16)(p5 * d5);
                    }
                }
                lpreg[b8] = blk;
            }
#undef SIG
        }
        __syncthreads();   // all dec reads done -> lpl aliases it

#pragma unroll
        for (int b8 = 0; b8 < 4; ++b8) {
            int q = u * 4 + b8;
            *(f16x8*)&lpl[tt * 4096 + lrow * 64 + ((q ^ (lrow & 7)) << 3)] = lpreg[b8];
        }
        __syncthreads();   // lpl visible

        // ---- GEMM2 partial: oacc2 += lpl[this wave's 16 rows] @ w2T[2 trees]
        // A-frag read = same swizzled-chunk pattern (conflict-free);
        // B direct from global w2T (L2-resident, 0.92 MB total).
        {
            const int tree0 = cb * 2;
            const int rbase = wid * 16;
#pragma unroll
            for (int t = 0; t < 2; ++t) {
                const _Float16* bp = w2T + (size_t)(tree0 + t) * (CPAD * LL) + (size_t)l15 * 64;
                const _Float16* lplt = lpl + t * 4096;
#pragma unroll
                for (int ks = 0; ks < 2; ++ks) {
                    const int sw = (((ks << 2) | quad) ^ (l15 & 7)) << 3;
                    f16x8 bbv[7], abv;
#pragma unroll
                    for (int ni = 0; ni < 7; ++ni)       // global first (latency)
                        bbv[ni] = *(const f16x8*)(bp + ni * 16 * 64 + sw);
                    abv = *(const f16x8*)&lplt[(rbase + l15) * 64 + sw];
#pragma unroll
                    for (int ni = 0; ni < 7; ++ni)
                        oacc2[ni] = __builtin_amdgcn_mfma_f32_16x16x32_f16(
                            abv, bbv[ni], oacc2[ni], 0, 0, 0);
                }
            }
        }
        // next group's first __syncthreads() protects lpl before restaging
    }

    // ---- epilogue: atomically accumulate this treechunk's 64x112 partial.
    // 28 atomics/thread x 256 thr x 1024 blocks = 7.3M (R1-proven level).
    {
        const int rbase2 = rb * 64 + wid * 16 + 4 * quad;
#pragma unroll
        for (int ni = 0; ni < 7; ++ni) {
            int col = 16 * ni + l15;
            if (col < CC) {
#pragma unroll
                for (int r = 0; r < 4; ++r)
                    unsafeAtomicAdd(&out[(size_t)(rbase2 + r) * CC + col],
                                    oacc2[ni][r]);
            }
        }
    }
}

// ---------------------------------------------------------------------------
extern "C" void kernel_launch(void* const* d_in, const int* in_sizes, int n_in,
                              void* d_out, int out_size, void* d_ws, size_t ws_size,
                              hipStream_t stream) {
    const float* x  = (const float*)d_in[0];   // [8192][512]
    const float* sw = (const float*)d_in[1];   // [64][63][512]
    const float* sb = (const float*)d_in[2];   // [64][63]
    const float* ll = (const float*)d_in[3];   // [64][64][100]
    const float* tw = (const float*)d_in[4];   // [64]
    float* out = (float*)d_out;                // [8192][100]
    _Float16* xh  = (_Float16*)((char*)d_ws + XH_WS);
    _Float16* swh = (_Float16*)((char*)d_ws + SWH_WS);
    _Float16* w2T = (_Float16*)((char*)d_ws + W2T_WS);

    prep_kernel<<<dim3(4896), 256, 0, stream>>>(x, sw, ll, tw, xh, swh, w2T, out);
    fused_kernel<<<dim3(128, 8), 256, 0, stream>>>(xh, swh, sb, w2T, out);
}